// Round 17
// baseline (55.417 us; speedup 1.0000x reference)
//
#include <hip/hip_runtime.h>

#define BB 8
#define NN 2048
#define DIN 128
#define DOUT 64
#define ALPHA_NS 0.2f
#define ITILE 16
#define JTILE 64
#define NWAVE 4
#define TTOT (NN / (JTILE * NWAVE))  // 8 tiles per wave

typedef __attribute__((ext_vector_type(4))) int int4v;
typedef __attribute__((ext_vector_type(4))) short short4v;
typedef __attribute__((ext_vector_type(4))) unsigned short ushort4v;
typedef __attribute__((ext_vector_type(4))) float float4v;

__device__ __forceinline__ unsigned short f32_to_bf16_rne(float x) {
  unsigned u = __builtin_bit_cast(unsigned, x);
  u += 0x7FFFu + ((u >> 16) & 1u);
  return (unsigned short)(u >> 16);
}

// ---- Kernel A: zproj. z = h@W -> zF fragment-order tiles, s1, s2m. ----
// s2m[j] = mask_j ? s2[j] : -30000  (masked j: exp(leaky(s1+s2m)) == 0.0f)
// zF tile jb (64 j x 64 d): element (d = dt*16+c, jj = ks*16 + kg*4 + r) at
//   (b*32+jb)*4096 + (dt*4+ks)*256 + (kg*16+c)*4 + r   (ushorts)  [R6-proven]
__global__ __launch_bounds__(256, 4) void gat_zproj(
    const float* __restrict__ h, const float* __restrict__ W,
    const float* __restrict__ a, const int* __restrict__ mask,
    unsigned short* __restrict__ zF, float* __restrict__ s1,
    float* __restrict__ s2) {
  __shared__ float shbuf[6144];  // union: hS (8KB) + accW (16KB)
  const int tid = threadIdx.x;
  const int w = tid >> 6, lane = tid & 63;
  const int zbid = blockIdx.x;  // 0..1023
  const long r0 = (long)zbid * 16;
  float (*hS)[DIN] = reinterpret_cast<float(*)[DIN]>(shbuf);
  float (*accW)[16][DOUT] =
      reinterpret_cast<float(*)[16][DOUT]>(shbuf + 16 * DIN);

  float Wr[32];
#pragma unroll
  for (int kk = 0; kk < 32; ++kk) Wr[kk] = W[(w * 32 + kk) * DOUT + lane];

  {
    const int r = tid >> 4, c = (tid & 15) * 8;
    const float* src = h + (r0 + r) * DIN + c;
    *reinterpret_cast<float4*>(&hS[r][c]) = *reinterpret_cast<const float4*>(src);
    *reinterpret_cast<float4*>(&hS[r][c + 4]) =
        *reinterpret_cast<const float4*>(src + 4);
  }
  __syncthreads();

#pragma unroll
  for (int r = 0; r < 16; ++r) {
    float acc = 0.f;
#pragma unroll
    for (int k4 = 0; k4 < 8; ++k4) {
      const float4 h4 = *reinterpret_cast<const float4*>(&hS[r][w * 32 + k4 * 4]);
      acc = fmaf(h4.x, Wr[k4 * 4 + 0], acc);
      acc = fmaf(h4.y, Wr[k4 * 4 + 1], acc);
      acc = fmaf(h4.z, Wr[k4 * 4 + 2], acc);
      acc = fmaf(h4.w, Wr[k4 * 4 + 3], acc);
    }
    accW[w][r][lane] = acc;
  }
  __syncthreads();

  unsigned short zt4[4];
#pragma unroll
  for (int it = 0; it < 4; ++it) {
    const int i = w * 4 + it;
    const int d = lane;
    const float zv =
        accW[0][i][d] + accW[1][i][d] + accW[2][i][d] + accW[3][i][d];
    zt4[it] = f32_to_bf16_rne(zv);
    float v1 = zv * a[d];
    float v2 = zv * a[DOUT + d];
#pragma unroll
    for (int off = 32; off; off >>= 1) {
      v1 += __shfl_xor(v1, off);
      v2 += __shfl_xor(v2, off);
    }
    if (lane == 0) {
      s1[r0 + i] = v1;
      s2[r0 + i] = (mask[r0 + i] > 0) ? v2 : -30000.0f;  // mask_j folded
    }
  }
  {
    const int b = zbid >> 7;
    const int bloc = zbid & 127;
    const int jb = bloc >> 2;
    const int ks = bloc & 3;
    const int dt = lane >> 4, row16 = lane & 15;
    ushort4v v;
    v.x = zt4[0]; v.y = zt4[1]; v.z = zt4[2]; v.w = zt4[3];
    const size_t e = ((size_t)(b * 32 + jb)) * 4096 +
                     (size_t)(((dt * 4 + ks) * 64 + w * 16 + row16) * 4);
    *reinterpret_cast<ushort4v*>(zF + e) = v;
  }
}

// One pipeline step for tile T, consuming adj/s2 register set (AQ, SV) and
// reloading that set with tile T+2. bfr refilled with tile T+1 mid-phase.
#define GAT_STEP(T, AQ, SV)                                                    \
  {                                                                            \
    const int t_ = (T);                                                        \
    unsigned g = 0;                                                            \
    _Pragma("unroll") for (int q = 0; q < 4; ++q) {                            \
      g |= (AQ[q].x > 0 ? 1u : 0u) << (q * 4 + 0);                             \
      g |= (AQ[q].y > 0 ? 1u : 0u) << (q * 4 + 1);                             \
      g |= (AQ[q].z > 0 ? 1u : 0u) << (q * 4 + 2);                             \
      g |= (AQ[q].w > 0 ? 1u : 0u) << (q * 4 + 3);                             \
    }                                                                          \
    if (t_ + 2 < TTOT) {                                                       \
      const int j0n = ((t_ + 2) * NWAVE + w) * JTILE;                          \
      _Pragma("unroll") for (int q = 0; q < 4; ++q)                            \
          AQ[q] = *reinterpret_cast<const int4v*>(                             \
              abase + (size_t)(q * 4 + rq) * NN + j0n + jq);                   \
    }                                                                          \
    _Pragma("unroll") for (int q = 0; q < 4; ++q) {                            \
      float sc0 = s1q[q] + SV.x;                                               \
      float sc1 = s1q[q] + SV.y;                                               \
      float sc2 = s1q[q] + SV.z;                                               \
      float sc3 = s1q[q] + SV.w;                                               \
      sc0 = fmaxf(sc0, ALPHA_NS * sc0);                                        \
      sc1 = fmaxf(sc1, ALPHA_NS * sc1);                                        \
      sc2 = fmaxf(sc2, ALPHA_NS * sc2);                                        \
      sc3 = fmaxf(sc3, ALPHA_NS * sc3);                                        \
      float p0 = ((g >> (q * 4 + 0)) & 1u) ? __expf(sc0) : 0.f;                \
      float p1 = ((g >> (q * 4 + 1)) & 1u) ? __expf(sc1) : 0.f;                \
      float p2 = ((g >> (q * 4 + 2)) & 1u) ? __expf(sc2) : 0.f;                \
      float p3 = ((g >> (q * 4 + 3)) & 1u) ? __expf(sc3) : 0.f;                \
      if (!((mbits >> q) & 1u)) { p0 = p1 = p2 = p3 = 1.0f; }                  \
      unsigned lo, hi;                                                         \
      asm("v_cvt_pk_bf16_f32 %0, %1, %2" : "=v"(lo) : "v"(p0), "v"(p1));       \
      asm("v_cvt_pk_bf16_f32 %0, %1, %2" : "=v"(hi) : "v"(p2), "v"(p3));       \
      lrow[q] += __builtin_bit_cast(float, lo << 16) +                         \
                 __builtin_bit_cast(float, lo & 0xFFFF0000u) +                 \
                 __builtin_bit_cast(float, hi << 16) +                         \
                 __builtin_bit_cast(float, hi & 0xFFFF0000u);                  \
      uint2 pk; pk.x = lo; pk.y = hi;                                          \
      *reinterpret_cast<uint2*>(&pA[w][q * 4 + rq][jq]) = pk;                  \
    }                                                                          \
    if (t_ + 2 < TTOT) {                                                       \
      const int j0n = ((t_ + 2) * NWAVE + w) * JTILE;                          \
      SV = *reinterpret_cast<const float4*>(s2g + b * NN + j0n + jq);          \
    }                                                                          \
    const unsigned short* tn = ztb + (size_t)((t_ + 1) * NWAVE + w) * 4096;    \
    __builtin_amdgcn_s_setprio(1);                                             \
    _Pragma("unroll") for (int ks = 0; ks < 2; ++ks) {                         \
      const short4v af = __builtin_bit_cast(                                   \
          short4v, *reinterpret_cast<const ushort4v*>(                         \
                       &pA[w][row16][ks * 16 + kgrp * 4]));                    \
      _Pragma("unroll") for (int dt = 0; dt < 4; ++dt)                         \
          acc[dt] = __builtin_amdgcn_mfma_f32_16x16x16bf16_1k(                 \
              af, bfr[ks * 4 + dt], acc[dt], 0, 0, 0);                         \
    }                                                                          \
    __builtin_amdgcn_s_setprio(0);                                             \
    if (t_ + 1 < TTOT) {                                                       \
      _Pragma("unroll") for (int ks = 0; ks < 2; ++ks)                         \
          _Pragma("unroll") for (int dt = 0; dt < 4; ++dt)                     \
              bfr[ks * 4 + dt] = __builtin_bit_cast(                           \
                  short4v, *reinterpret_cast<const ushort4v*>(                 \
                               tn + (dt * 4 + ks) * 256));                     \
    }                                                                          \
    __builtin_amdgcn_s_setprio(1);                                             \
    _Pragma("unroll") for (int ks = 2; ks < 4; ++ks) {                         \
      const short4v af = __builtin_bit_cast(                                   \
          short4v, *reinterpret_cast<const ushort4v*>(                         \
                       &pA[w][row16][ks * 16 + kgrp * 4]));                    \
      _Pragma("unroll") for (int dt = 0; dt < 4; ++dt)                         \
          acc[dt] = __builtin_amdgcn_mfma_f32_16x16x16bf16_1k(                 \
              af, bfr[ks * 4 + dt], acc[dt], 0, 0, 0);                         \
    }                                                                          \
    __builtin_amdgcn_s_setprio(0);                                             \
    if (t_ + 1 < TTOT) {                                                       \
      _Pragma("unroll") for (int ks = 2; ks < 4; ++ks)                         \
          _Pragma("unroll") for (int dt = 0; dt < 4; ++dt)                     \
              bfr[ks * 4 + dt] = __builtin_bit_cast(                           \
                  short4v, *reinterpret_cast<const ushort4v*>(                 \
                               tn + (dt * 4 + ks) * 256));                     \
    }                                                                          \
  }

// ---- Kernel B: R15 datapath + depth-2 adj/s2 prefetch (A/B reg sets) ----
// 1024 blocks (XCD-chunked bijective swizzle: XCD k owns batch k), 4 waves.
__global__ __launch_bounds__(256, 4) void gat_attn(
    const unsigned short* __restrict__ zF, const float* __restrict__ s1g,
    const float* __restrict__ s2g, const int* __restrict__ adj,
    const int* __restrict__ mask, float* __restrict__ out) {
  const int lid = (blockIdx.x & 7) * 128 + (blockIdx.x >> 3);
  const int b = lid >> 7;
  const int i0 = (lid & 127) * ITILE;
  const int tid = threadIdx.x;
  const int w = tid >> 6, lane = tid & 63;
  const int row16 = lane & 15, kgrp = lane >> 4;
  const int rq = lane >> 4;            // row sub-index for adj mapping
  const int jq = (lane & 15) * 4;      // j offset (4 consecutive) in tile

  __shared__ __align__(16) unsigned short pA[NWAVE][ITILE][72];  // 9.2 KB
  __shared__ float accS[NWAVE][ITILE][DOUT];                     // 16 KB
  __shared__ float Lred[NWAVE][ITILE];

  float s1q[4];
  unsigned mbits = 0;
#pragma unroll
  for (int q = 0; q < 4; ++q) {
    s1q[q] = s1g[b * NN + i0 + q * 4 + rq];
    mbits |= (mask[b * NN + i0 + q * 4 + rq] > 0 ? 1u : 0u) << q;
  }

  float4v acc[4];
#pragma unroll
  for (int dt = 0; dt < 4; ++dt) acc[dt] = (float4v){0.f, 0.f, 0.f, 0.f};
  float lrow[4] = {0.f, 0.f, 0.f, 0.f};  // denom partials (bf16-rounded p)

  const int* abase = adj + (size_t)(b * NN + i0) * NN;
  const unsigned short* ztb = zF + (size_t)(b * 32) * 4096 + lane * 4;

  // ---- prologue: depth-2 adj/s2 (tiles 0,1 into A,B), tile-0 zF frags ----
  int4v adjA[4], adjB[4];
  float4 s2A, s2B;
#pragma unroll
  for (int q = 0; q < 4; ++q)
    adjA[q] = *reinterpret_cast<const int4v*>(
        abase + (size_t)(q * 4 + rq) * NN + (0 * NWAVE + w) * JTILE + jq);
  s2A = *reinterpret_cast<const float4*>(s2g + b * NN + (0 * NWAVE + w) * JTILE + jq);
#pragma unroll
  for (int q = 0; q < 4; ++q)
    adjB[q] = *reinterpret_cast<const int4v*>(
        abase + (size_t)(q * 4 + rq) * NN + (1 * NWAVE + w) * JTILE + jq);
  s2B = *reinterpret_cast<const float4*>(s2g + b * NN + (1 * NWAVE + w) * JTILE + jq);

  short4v bfr[16];
  {
    const unsigned short* t0 = ztb + (size_t)w * 4096;
#pragma unroll
    for (int ks = 0; ks < 4; ++ks)
#pragma unroll
      for (int dt = 0; dt < 4; ++dt)
        bfr[ks * 4 + dt] = __builtin_bit_cast(
            short4v,
            *reinterpret_cast<const ushort4v*>(t0 + (dt * 4 + ks) * 256));
  }

#pragma unroll 1
  for (int tt = 0; tt < TTOT; tt += 2) {
    GAT_STEP(tt, adjA, s2A);      // consumes A (tile tt),   reloads A <- tt+2
    GAT_STEP(tt + 1, adjB, s2B);  // consumes B (tile tt+1), reloads B <- tt+3
  }

  // ---- denominator: reduce lrow over the 16 j-lanes of each rq group ----
#pragma unroll
  for (int q = 0; q < 4; ++q) {
    lrow[q] += __shfl_xor(lrow[q], 1);
    lrow[q] += __shfl_xor(lrow[q], 2);
    lrow[q] += __shfl_xor(lrow[q], 4);
    lrow[q] += __shfl_xor(lrow[q], 8);
  }
  if ((lane & 15) == 0) {
#pragma unroll
    for (int q = 0; q < 4; ++q) Lred[w][q * 4 + rq] = lrow[q];
  }
  // ---- stash per-wave PV partials ----
#pragma unroll
  for (int dt = 0; dt < 4; ++dt) {
#pragma unroll
    for (int r = 0; r < 4; ++r)
      accS[w][kgrp * 4 + r][dt * 16 + row16] = acc[dt][r];
  }
  __syncthreads();

  // ---- epilogue: combine waves, divide, ELU, store ----
#pragma unroll
  for (int it = 0; it < 4; ++it) {
    const int i = (tid >> 6) + it * 4;
    const int d = tid & 63;
    const float L = Lred[0][i] + Lred[1][i] + Lred[2][i] + Lred[3][i];
    const float v = accS[0][i][d] + accS[1][i][d] + accS[2][i][d] + accS[3][i][d];
    const float hp = v / L;
    const float r = hp > 0.f ? hp : (__expf(hp) - 1.f);
    out[((long)b * NN + i0 + i) * DOUT + d] = r;
  }
}

extern "C" void kernel_launch(void* const* d_in, const int* in_sizes, int n_in,
                              void* d_out, int out_size, void* d_ws, size_t ws_size,
                              hipStream_t stream) {
  const float* h = (const float*)d_in[0];
  const int* adj = (const int*)d_in[1];
  const int* mask = (const int*)d_in[2];
  const float* W = (const float*)d_in[3];
  const float* a = (const float*)d_in[4];
  float* out = (float*)d_out;

  unsigned short* zF = (unsigned short*)d_ws;                   // 2 MB
  float* s1 = (float*)((char*)d_ws + (size_t)BB * NN * DOUT * 2);
  float* s2 = s1 + (size_t)BB * NN;

  gat_zproj<<<dim3(1024), dim3(256), 0, stream>>>(h, W, a, mask, zF, s1, s2);
  gat_attn<<<dim3(NN / ITILE * BB), dim3(256), 0, stream>>>(zF, s1, s2, adj,
                                                            mask, out);
}

// Round 18
// 43.049 us; speedup vs baseline: 1.2873x; 1.2873x over previous
//
#include <hip/hip_runtime.h>

#define BB 8
#define NN 2048
#define DIN 128
#define DOUT 64
#define ALPHA_NS 0.2f
#define ITILE 16
#define JTILE 64
#define NWAVE 4
#define TTOT (NN / (JTILE * NWAVE))  // 8 tiles per wave

typedef __attribute__((ext_vector_type(4))) int int4v;
typedef __attribute__((ext_vector_type(4))) short short4v;
typedef __attribute__((ext_vector_type(4))) unsigned short ushort4v;
typedef __attribute__((ext_vector_type(4))) float float4v;

__device__ __forceinline__ unsigned short f32_to_bf16_rne(float x) {
  unsigned u = __builtin_bit_cast(unsigned, x);
  u += 0x7FFFu + ((u >> 16) & 1u);
  return (unsigned short)(u >> 16);
}

// ---- Kernel A: zproj. z = h@W -> zF fragment-order tiles, s1, s2m. ----
// s2m[j] = mask_j ? s2[j] : -30000  (masked j: exp(leaky(s1+s2m)) == 0.0f)
// zF tile jb (64 j x 64 d): element (d = dt*16+c, jj = ks*16 + kg*4 + r) at
//   (b*32+jb)*4096 + (dt*4+ks)*256 + (kg*16+c)*4 + r   (ushorts)  [R6-proven]
__global__ __launch_bounds__(256, 4) void gat_zproj(
    const float* __restrict__ h, const float* __restrict__ W,
    const float* __restrict__ a, const int* __restrict__ mask,
    unsigned short* __restrict__ zF, float* __restrict__ s1,
    float* __restrict__ s2) {
  __shared__ float shbuf[6144];  // union: hS (8KB) + accW (16KB)
  const int tid = threadIdx.x;
  const int w = tid >> 6, lane = tid & 63;
  const int zbid = blockIdx.x;  // 0..1023
  const long r0 = (long)zbid * 16;
  float (*hS)[DIN] = reinterpret_cast<float(*)[DIN]>(shbuf);
  float (*accW)[16][DOUT] =
      reinterpret_cast<float(*)[16][DOUT]>(shbuf + 16 * DIN);

  float Wr[32];
#pragma unroll
  for (int kk = 0; kk < 32; ++kk) Wr[kk] = W[(w * 32 + kk) * DOUT + lane];

  {
    const int r = tid >> 4, c = (tid & 15) * 8;
    const float* src = h + (r0 + r) * DIN + c;
    *reinterpret_cast<float4*>(&hS[r][c]) = *reinterpret_cast<const float4*>(src);
    *reinterpret_cast<float4*>(&hS[r][c + 4]) =
        *reinterpret_cast<const float4*>(src + 4);
  }
  __syncthreads();

#pragma unroll
  for (int r = 0; r < 16; ++r) {
    float acc = 0.f;
#pragma unroll
    for (int k4 = 0; k4 < 8; ++k4) {
      const float4 h4 = *reinterpret_cast<const float4*>(&hS[r][w * 32 + k4 * 4]);
      acc = fmaf(h4.x, Wr[k4 * 4 + 0], acc);
      acc = fmaf(h4.y, Wr[k4 * 4 + 1], acc);
      acc = fmaf(h4.z, Wr[k4 * 4 + 2], acc);
      acc = fmaf(h4.w, Wr[k4 * 4 + 3], acc);
    }
    accW[w][r][lane] = acc;
  }
  __syncthreads();

  unsigned short zt4[4];
#pragma unroll
  for (int it = 0; it < 4; ++it) {
    const int i = w * 4 + it;
    const int d = lane;
    const float zv =
        accW[0][i][d] + accW[1][i][d] + accW[2][i][d] + accW[3][i][d];
    zt4[it] = f32_to_bf16_rne(zv);
    float v1 = zv * a[d];
    float v2 = zv * a[DOUT + d];
#pragma unroll
    for (int off = 32; off; off >>= 1) {
      v1 += __shfl_xor(v1, off);
      v2 += __shfl_xor(v2, off);
    }
    if (lane == 0) {
      s1[r0 + i] = v1;
      s2[r0 + i] = (mask[r0 + i] > 0) ? v2 : -30000.0f;  // mask_j folded
    }
  }
  {
    const int b = zbid >> 7;
    const int bloc = zbid & 127;
    const int jb = bloc >> 2;
    const int ks = bloc & 3;
    const int dt = lane >> 4, row16 = lane & 15;
    ushort4v v;
    v.x = zt4[0]; v.y = zt4[1]; v.z = zt4[2]; v.w = zt4[3];
    const size_t e = ((size_t)(b * 32 + jb)) * 4096 +
                     (size_t)(((dt * 4 + ks) * 64 + w * 16 + row16) * 4);
    *reinterpret_cast<ushort4v*>(zF + e) = v;
  }
}

// ---- Kernel B: adj streamed directly + softmax + PV (bf16 MFMA) + ELU ----
// 1024 blocks (XCD-chunked bijective swizzle: XCD k owns batch k), 4 waves.
// Per wave-tile: 4 x int4 adj loads (1KB/instr), lane owns rows {4q+rq},
// j's jq..jq+3.  [R11 champion datapath, verbatim]
__global__ __launch_bounds__(256, 4) void gat_attn(
    const unsigned short* __restrict__ zF, const float* __restrict__ s1g,
    const float* __restrict__ s2g, const int* __restrict__ adj,
    const int* __restrict__ mask, float* __restrict__ out) {
  const int lid = (blockIdx.x & 7) * 128 + (blockIdx.x >> 3);
  const int b = lid >> 7;
  const int i0 = (lid & 127) * ITILE;
  const int tid = threadIdx.x;
  const int w = tid >> 6, lane = tid & 63;
  const int row16 = lane & 15, kgrp = lane >> 4;
  const int rq = lane >> 4;            // row sub-index for adj mapping
  const int jq = (lane & 15) * 4;      // j offset (4 consecutive) in tile

  __shared__ __align__(16) unsigned short pA[NWAVE][ITILE][72];  // 9.2 KB
  __shared__ float accS[NWAVE][ITILE][DOUT];                     // 16 KB
  __shared__ float Lred[NWAVE][ITILE];

  // per-lane: s1 for rows 4q+rq, and mask nibble (bit q = row 4q+rq unmasked)
  float s1q[4];
  unsigned mbits = 0;
#pragma unroll
  for (int q = 0; q < 4; ++q) {
    s1q[q] = s1g[b * NN + i0 + q * 4 + rq];
    mbits |= (mask[b * NN + i0 + q * 4 + rq] > 0 ? 1u : 0u) << q;
  }

  float4v acc[5];
#pragma unroll
  for (int dt = 0; dt < 5; ++dt) acc[dt] = (float4v){0.f, 0.f, 0.f, 0.f};

  // ones B-fragment (col 0) -> denominator via MFMA
  const short4v ones =
      (row16 == 0) ? short4v{(short)0x3F80, (short)0x3F80, (short)0x3F80,
                             (short)0x3F80}
                   : short4v{0, 0, 0, 0};

  const int* abase = adj + (size_t)(b * NN + i0) * NN;
  const unsigned short* ztb = zF + (size_t)(b * 32) * 4096 + lane * 4;

  // ---- prologue: tile-0 adj (4 x int4), s2 quad, zF fragments ----
  int4v adjq[4];
#pragma unroll
  for (int q = 0; q < 4; ++q)
    adjq[q] = *reinterpret_cast<const int4v*>(
        abase + (size_t)(q * 4 + rq) * NN + w * JTILE + jq);
  float4 s2v = *reinterpret_cast<const float4*>(s2g + b * NN + w * JTILE + jq);
  short4v bfr[16];
  {
    const unsigned short* t0 = ztb + (size_t)w * 4096;
#pragma unroll
    for (int ks = 0; ks < 4; ++ks)
#pragma unroll
      for (int dt = 0; dt < 4; ++dt)
        bfr[ks * 4 + dt] = __builtin_bit_cast(
            short4v,
            *reinterpret_cast<const ushort4v*>(t0 + (dt * 4 + ks) * 256));
  }

#pragma unroll 1
  for (int t = 0; t < TTOT; ++t) {
    // ---- phase 1: scores -> p (bf16), 4 x 8B ds_writes ----
#pragma unroll
    for (int q = 0; q < 4; ++q) {
      float sc0 = s1q[q] + s2v.x;
      float sc1 = s1q[q] + s2v.y;
      float sc2 = s1q[q] + s2v.z;
      float sc3 = s1q[q] + s2v.w;
      sc0 = fmaxf(sc0, ALPHA_NS * sc0);
      sc1 = fmaxf(sc1, ALPHA_NS * sc1);
      sc2 = fmaxf(sc2, ALPHA_NS * sc2);
      sc3 = fmaxf(sc3, ALPHA_NS * sc3);
      float p0 = (adjq[q].x > 0) ? __expf(sc0) : 0.f;
      float p1 = (adjq[q].y > 0) ? __expf(sc1) : 0.f;
      float p2 = (adjq[q].z > 0) ? __expf(sc2) : 0.f;
      float p3 = (adjq[q].w > 0) ? __expf(sc3) : 0.f;
      if (!((mbits >> q) & 1u)) {  // masked-i row: exact mean via p=1
        p0 = p1 = p2 = p3 = 1.0f;
      }
      unsigned lo, hi;
      asm("v_cvt_pk_bf16_f32 %0, %1, %2" : "=v"(lo) : "v"(p0), "v"(p1));
      asm("v_cvt_pk_bf16_f32 %0, %1, %2" : "=v"(hi) : "v"(p2), "v"(p3));
      uint2 pk; pk.x = lo; pk.y = hi;
      *reinterpret_cast<uint2*>(&pA[w][q * 4 + rq][jq]) = pk;
    }
    // ---- issue t+1 adj/s2 (covered by phase 2 + wave interleave) ----
    if (t + 1 < TTOT) {
      const int j0n = ((t + 1) * NWAVE + w) * JTILE;
#pragma unroll
      for (int q = 0; q < 4; ++q)
        adjq[q] = *reinterpret_cast<const int4v*>(
            abase + (size_t)(q * 4 + rq) * NN + j0n + jq);
      s2v = *reinterpret_cast<const float4*>(s2g + b * NN + j0n + jq);
    }
    const unsigned short* tn = ztb + (size_t)((t + 1) * NWAVE + w) * 4096;
    // ---- phase 2a: ks = 0,1 ----
    __builtin_amdgcn_s_setprio(1);
#pragma unroll
    for (int ks = 0; ks < 2; ++ks) {
      const short4v af = __builtin_bit_cast(
          short4v,
          *reinterpret_cast<const ushort4v*>(&pA[w][row16][ks * 16 + kgrp * 4]));
      acc[4] =
          __builtin_amdgcn_mfma_f32_16x16x16bf16_1k(af, ones, acc[4], 0, 0, 0);
#pragma unroll
      for (int dt = 0; dt < 4; ++dt)
        acc[dt] = __builtin_amdgcn_mfma_f32_16x16x16bf16_1k(af, bfr[ks * 4 + dt],
                                                            acc[dt], 0, 0, 0);
    }
    __builtin_amdgcn_s_setprio(0);
    if (t + 1 < TTOT) {
#pragma unroll
      for (int ks = 0; ks < 2; ++ks)
#pragma unroll
        for (int dt = 0; dt < 4; ++dt)
          bfr[ks * 4 + dt] = __builtin_bit_cast(
              short4v,
              *reinterpret_cast<const ushort4v*>(tn + (dt * 4 + ks) * 256));
    }
    // ---- phase 2b: ks = 2,3 ----
    __builtin_amdgcn_s_setprio(1);
#pragma unroll
    for (int ks = 2; ks < 4; ++ks) {
      const short4v af = __builtin_bit_cast(
          short4v,
          *reinterpret_cast<const ushort4v*>(&pA[w][row16][ks * 16 + kgrp * 4]));
      acc[4] =
          __builtin_amdgcn_mfma_f32_16x16x16bf16_1k(af, ones, acc[4], 0, 0, 0);
#pragma unroll
      for (int dt = 0; dt < 4; ++dt)
        acc[dt] = __builtin_amdgcn_mfma_f32_16x16x16bf16_1k(af, bfr[ks * 4 + dt],
                                                            acc[dt], 0, 0, 0);
    }
    __builtin_amdgcn_s_setprio(0);
    if (t + 1 < TTOT) {
#pragma unroll
      for (int ks = 2; ks < 4; ++ks)
#pragma unroll
        for (int dt = 0; dt < 4; ++dt)
          bfr[ks * 4 + dt] = __builtin_bit_cast(
              short4v,
              *reinterpret_cast<const ushort4v*>(tn + (dt * 4 + ks) * 256));
    }
  }

  // ---- stash per-wave partials ----
  if (row16 == 0) {
#pragma unroll
    for (int r = 0; r < 4; ++r) Lred[w][kgrp * 4 + r] = acc[4][r];
  }
#pragma unroll
  for (int dt = 0; dt < 4; ++dt) {
#pragma unroll
    for (int r = 0; r < 4; ++r)
      accS[w][kgrp * 4 + r][dt * 16 + row16] = acc[dt][r];
  }
  __syncthreads();

  // ---- epilogue: combine waves, divide, ELU, store ----
#pragma unroll
  for (int it = 0; it < 4; ++it) {
    const int i = (tid >> 6) + it * 4;
    const int d = tid & 63;
    const float L = Lred[0][i] + Lred[1][i] + Lred[2][i] + Lred[3][i];
    const float v = accS[0][i][d] + accS[1][i][d] + accS[2][i][d] + accS[3][i][d];
    const float hp = v / L;
    const float r = hp > 0.f ? hp : (__expf(hp) - 1.f);
    out[((long)b * NN + i0 + i) * DOUT + d] = r;
  }
}

extern "C" void kernel_launch(void* const* d_in, const int* in_sizes, int n_in,
                              void* d_out, int out_size, void* d_ws, size_t ws_size,
                              hipStream_t stream) {
  const float* h = (const float*)d_in[0];
  const int* adj = (const int*)d_in[1];
  const int* mask = (const int*)d_in[2];
  const float* W = (const float*)d_in[3];
  const float* a = (const float*)d_in[4];
  float* out = (float*)d_out;

  unsigned short* zF = (unsigned short*)d_ws;                   // 2 MB
  float* s1 = (float*)((char*)d_ws + (size_t)BB * NN * DOUT * 2);
  float* s2 = s1 + (size_t)BB * NN;

  gat_zproj<<<dim3(1024), dim3(256), 0, stream>>>(h, W, a, mask, zF, s1, s2);
  gat_attn<<<dim3(NN / ITILE * BB), dim3(256), 0, stream>>>(zF, s1, s2, adj,
                                                            mask, out);
}